// Round 1
// baseline (1846.546 us; speedup 1.0000x reference)
//
#include <hip/hip_runtime.h>
#include <math.h>

#define BATCH 16
#define SEQ   1024
#define DIM   2048
#define EPS_F 0.1f
#define INV_EPS 10.0f
#define N_ITER 100

typedef short bf16x8 __attribute__((ext_vector_type(8)));
typedef float f32x4  __attribute__((ext_vector_type(4)));

__device__ inline float blo(unsigned int x) { return __uint_as_float(x << 16); }
__device__ inline float bhi(unsigned int x) { return __uint_as_float(x & 0xffff0000u); }

__device__ inline unsigned short f_to_bf16(float f) {
    unsigned int x = __float_as_uint(f);
    unsigned int lsb = (x >> 16) & 1u;
    x += 0x7fffu + lsb;               // round-to-nearest-even
    return (unsigned short)(x >> 16);
}

// ---------------- init: t buffers = 0, flags = 0 ----------------
__global__ void init_state(float* __restrict__ tbuf, unsigned int* __restrict__ flags) {
    int i = blockIdx.x * 256 + threadIdx.x;   // grid 64*256 = 16384
    ((float4*)tbuf)[i] = (float4){0.f, 0.f, 0.f, 0.f};
    if (i < 1024) flags[i] = 0u;
}

// ---------------- normalize + cast to bf16 ----------------
__global__ __launch_bounds__(256) void normalize_kernel(
    const float* __restrict__ student, const float* __restrict__ teacher,
    unsigned short* __restrict__ Sn, unsigned short* __restrict__ Tn)
{
    int rowid  = blockIdx.x;
    int tensor = rowid >> 14;
    int row    = rowid & 16383;
    const float* src = tensor ? teacher : student;
    unsigned short* dst = tensor ? Tn : Sn;
    const float4* p4 = (const float4*)(src + (size_t)row * DIM);
    int t = threadIdx.x;

    float4 a = p4[t];
    float4 b = p4[t + 256];
    float ss = a.x*a.x + a.y*a.y + a.z*a.z + a.w*a.w
             + b.x*b.x + b.y*b.y + b.z*b.z + b.w*b.w;
    #pragma unroll
    for (int m = 32; m; m >>= 1) ss += __shfl_xor(ss, m, 64);
    __shared__ float wss[4];
    if ((t & 63) == 0) wss[t >> 6] = ss;
    __syncthreads();
    float rn = 1.0f / fmaxf(sqrtf(wss[0] + wss[1] + wss[2] + wss[3]), 1e-12f);

    unsigned short o1[4], o2[4];
    o1[0] = f_to_bf16(a.x * rn); o1[1] = f_to_bf16(a.y * rn);
    o1[2] = f_to_bf16(a.z * rn); o1[3] = f_to_bf16(a.w * rn);
    o2[0] = f_to_bf16(b.x * rn); o2[1] = f_to_bf16(b.y * rn);
    o2[2] = f_to_bf16(b.z * rn); o2[3] = f_to_bf16(b.w * rn);
    unsigned short* d = dst + (size_t)row * DIM;
    *(uint2*)(d + 4*t)        = *(uint2*)o1;
    *(uint2*)(d + 1024 + 4*t) = *(uint2*)o2;
}

// ---------------- batched GEMM -> K = exp(-C/eps), bf16 ----------------
#define TM  128
#define BK  32
#define LDK 40

__global__ __launch_bounds__(256) void gemm_cost_kernel(
    const unsigned short* __restrict__ Tn, const unsigned short* __restrict__ Sn,
    unsigned short* __restrict__ Kmat)
{
    __shared__ unsigned short As[TM * LDK];
    __shared__ unsigned short Bs[TM * LDK];

    int bid  = blockIdx.x;
    int b    = bid >> 6;
    int tile = bid & 63;
    int tm0  = (tile >> 3) * TM;
    int tn0  = (tile & 7)  * TM;

    const unsigned short* Ab = Tn + (size_t)b * SEQ * DIM;
    const unsigned short* Bb = Sn + (size_t)b * SEQ * DIM;

    int t    = threadIdx.x;
    int w    = t >> 6;
    int l    = t & 63;
    int mq   = (w >> 1) * 64;
    int nq   = (w & 1)  * 64;
    int lrow = l & 15;
    int kg   = l >> 4;

    int srow = t >> 2;
    int sseg = t & 3;

    f32x4 acc[4][4];
    #pragma unroll
    for (int i = 0; i < 4; i++)
        #pragma unroll
        for (int j = 0; j < 4; j++)
            acc[i][j] = (f32x4){0.f, 0.f, 0.f, 0.f};

    for (int k0 = 0; k0 < DIM; k0 += BK) {
        const int4 va0 = *(const int4*)(Ab + (size_t)(tm0 + srow)      * DIM + k0 + sseg * 8);
        const int4 va1 = *(const int4*)(Ab + (size_t)(tm0 + srow + 64) * DIM + k0 + sseg * 8);
        const int4 vb0 = *(const int4*)(Bb + (size_t)(tn0 + srow)      * DIM + k0 + sseg * 8);
        const int4 vb1 = *(const int4*)(Bb + (size_t)(tn0 + srow + 64) * DIM + k0 + sseg * 8);
        __syncthreads();
        *(int4*)&As[(srow)      * LDK + sseg * 8] = va0;
        *(int4*)&As[(srow + 64) * LDK + sseg * 8] = va1;
        *(int4*)&Bs[(srow)      * LDK + sseg * 8] = vb0;
        *(int4*)&Bs[(srow + 64) * LDK + sseg * 8] = vb1;
        __syncthreads();

        bf16x8 af[4], bfr[4];
        #pragma unroll
        for (int i = 0; i < 4; i++)
            af[i] = *(const bf16x8*)&As[(mq + i * 16 + lrow) * LDK + kg * 8];
        #pragma unroll
        for (int j = 0; j < 4; j++)
            bfr[j] = *(const bf16x8*)&Bs[(nq + j * 16 + lrow) * LDK + kg * 8];
        #pragma unroll
        for (int i = 0; i < 4; i++)
            #pragma unroll
            for (int j = 0; j < 4; j++)
                acc[i][j] = __builtin_amdgcn_mfma_f32_16x16x32_bf16(af[i], bfr[j], acc[i][j], 0, 0, 0);
    }

    unsigned short* Kb = Kmat + ((size_t)b << 20);
    #pragma unroll
    for (int i = 0; i < 4; i++) {
        #pragma unroll
        for (int j = 0; j < 4; j++) {
            int gcol = tn0 + nq + j * 16 + lrow;
            #pragma unroll
            for (int r = 0; r < 4; r++) {
                int grow = tm0 + mq + i * 16 + kg * 4 + r;
                float cosv = acc[i][j][r];
                float cost = 0.5f - 0.5f * cosv;
                Kb[((size_t)grow << 10) + gcol] = f_to_bf16(__expf(-cost * INV_EPS));
            }
        }
    }
}

// ---------------- persistent Sinkhorn + fused loss ----------------
// 256 blocks x 512 threads. Block owns a 64-row strip of one batch.
// NEW in this round:
//   * K strip (128 KB bf16) preloaded into LDS once; all 100 iters + the
//     loss pass read LDS (kills per-iter L2 latency exposure and LLC churn).
//     Column-block XOR swizzle ((l*32)^(sw<<4)) spreads the ds_read_b128 row
//     reads over all 32 banks; the SAME xor is applied to the v LDS
//     *addresses* (never to register indices -> no scratch).
//   * rows processed in batches of 4: 4 dot chains, then 4 interleaved
//     butterfly reductions (serial shfl latency /4), then the held
//     registers are reused for the column partials.
//   * cross-wave t-reduce via ds_add_f32 into ONE 4 KB array (fits next to
//     the 128 KB K strip) with a bank-spreading XOR baked into the layout.
// Cross-block exchange (LLC atomics + flag barrier) is UNCHANGED.
#define UNPK(A,B,F) do { \
    F[0]=blo(A.x);  F[1]=bhi(A.x);  F[2]=blo(A.y);  F[3]=bhi(A.y);  \
    F[4]=blo(A.z);  F[5]=bhi(A.z);  F[6]=blo(A.w);  F[7]=bhi(A.w);  \
    F[8]=blo(B.x);  F[9]=bhi(B.x);  F[10]=blo(B.y); F[11]=bhi(B.y); \
    F[12]=blo(B.z); F[13]=bhi(B.z); F[14]=blo(B.w); F[15]=bhi(B.w); } while(0)

__global__ __launch_bounds__(512, 2) void sinkhorn_persistent(
    const unsigned short* __restrict__ Kmat,
    float* __restrict__ tbuf,          // [16][4][1024]
    unsigned int* __restrict__ flags,  // [16][64]
    float* __restrict__ partials)      // [256]
{
    __shared__ __align__(16) unsigned short Ks[64 * 1024]; // 128 KB K strip
    __shared__ float vsw[1024];        // v, swizzled: v[c] at (c&15)*64 + (c>>4)
    __shared__ float part[1024];       // column partial sums (ds_add_f32)
    __shared__ float ulds[64];
    __shared__ float wlds[8];

    int idx   = blockIdx.x;
    int b     = (idx & 7) | (((idx >> 3) & 1) << 3);  // idx%8 == b%8 : XCD-pinned
    int slice = idx >> 4;                             // 0..15
    const unsigned short* Kb = Kmat + ((size_t)b << 20);
    float* tb = tbuf + (b << 12);
    unsigned int* flag = flags + b * 64;

    int t    = threadIdx.x;
    int lane = t & 63;
    int w    = t >> 6;                 // wave 0..7
    int r0   = slice << 6;             // this block's 64 rows (also its 64-col zero-slice)

    // lane's logical column k (0..15) lives at col = lane*16 + (k ^ sw8);
    // sw swaps the two 8-col halves so ds_read_b128 covers all 32 banks.
    int sw   = (lane >> 2) & 1;
    int sw8  = sw << 3;
    int xa   = (lane << 5) ^ (sw << 4);   // byte offset of logical k0..7 block
    int xb   = xa ^ 16;                   // byte offset of logical k8..15 block
    int phx  = ((lane >> 1) & 1) << 2;    // part-layout bank spread (bit2 ^= lane bit1)
    const char* ksb = (const char*)Ks;

    // ---- one-time: preload K strip (contiguous 128 KB) + init ----
    {
        const int4* src = (const int4*)(Kb + ((size_t)r0 << 10));
        int4* dst = (int4*)Ks;
        #pragma unroll
        for (int i = 0; i < 16; i++) dst[t + i * 512] = src[t + i * 512];
    }
    vsw[t] = 1.0f; vsw[t + 512] = 1.0f;     // v0 = 1 (swizzle of ones is ones)
    part[t] = 0.f; part[t + 512] = 0.f;
    __syncthreads();

    unsigned int tgt = 0;
    for (int iter = 0; iter < N_ITER; iter++) {
        // vreg[k] = v[lane*16 + (k^sw8)] — runtime address, static reg index
        float vreg[16];
        #pragma unroll
        for (int k = 0; k < 16; k++) vreg[k] = vsw[((k ^ sw8) << 6) + lane];

        float tacc[16];
        #pragma unroll
        for (int k = 0; k < 16; k++) tacc[k] = 0.f;

        // ---- sweep: 2 batches of 4 rows, butterflies interleaved ----
        #pragma unroll
        for (int bb = 0; bb < 2; bb++) {
            const char* kr = ksb + (((w << 3) + (bb << 2)) << 11);
            uint4 a0 = *(const uint4*)(kr + xa);
            uint4 b0 = *(const uint4*)(kr + xb);
            uint4 a1 = *(const uint4*)(kr + 2048 + xa);
            uint4 b1 = *(const uint4*)(kr + 2048 + xb);
            uint4 a2 = *(const uint4*)(kr + 4096 + xa);
            uint4 b2 = *(const uint4*)(kr + 4096 + xb);
            uint4 a3 = *(const uint4*)(kr + 6144 + xa);
            uint4 b3 = *(const uint4*)(kr + 6144 + xb);
            float f0[16], f1[16], f2[16], f3[16];
            UNPK(a0, b0, f0); UNPK(a1, b1, f1);
            UNPK(a2, b2, f2); UNPK(a3, b3, f3);

            float s0 = 0.f, s1 = 0.f, s2 = 0.f, s3 = 0.f;
            #pragma unroll
            for (int k = 0; k < 16; k++) {
                s0 = fmaf(f0[k], vreg[k], s0);
                s1 = fmaf(f1[k], vreg[k], s1);
                s2 = fmaf(f2[k], vreg[k], s2);
                s3 = fmaf(f3[k], vreg[k], s3);
            }
            #pragma unroll
            for (int m = 32; m; m >>= 1) {   // 4 independent chains, pipelined
                s0 += __shfl_xor(s0, m, 64);
                s1 += __shfl_xor(s1, m, 64);
                s2 += __shfl_xor(s2, m, 64);
                s3 += __shfl_xor(s3, m, 64);
            }
            float u0 = (1.0f / 1024.0f) / s0;
            float u1 = (1.0f / 1024.0f) / s1;
            float u2 = (1.0f / 1024.0f) / s2;
            float u3 = (1.0f / 1024.0f) / s3;
            if (lane == 0) {
                int rb = (w << 3) + (bb << 2);
                ulds[rb] = u0; ulds[rb + 1] = u1; ulds[rb + 2] = u2; ulds[rb + 3] = u3;
            }
            #pragma unroll
            for (int k = 0; k < 16; k++) {
                tacc[k] = fmaf(f0[k], u0, tacc[k]);
                tacc[k] = fmaf(f1[k], u1, tacc[k]);
                tacc[k] = fmaf(f2[k], u2, tacc[k]);
                tacc[k] = fmaf(f3[k], u3, tacc[k]);
            }
        }
        // wave partials -> shared column sums (ds_add_f32, layout ^= phx)
        #pragma unroll
        for (int k = 0; k < 16; k++)
            atomicAdd(&part[((lane << 4) + (k ^ sw8)) ^ phx], tacc[k]);
        __syncthreads();

        // per-thread cols 2t,2t+1 -> LLC atomics; re-zero part for next iter
        int cur = iter & 3;
        float* tcur = tb + (cur << 10);
        int c0 = t * 2;
        int p0 = c0 ^ (((c0 >> 5) & 1) << 2);   // same layout bijection
        float2 pv = *(const float2*)&part[p0];
        atomicAdd(&tcur[c0],     pv.x);
        atomicAdd(&tcur[c0 + 1], pv.y);
        *(float2*)&part[p0] = (float2){0.f, 0.f};
        if (t < 64)
            __hip_atomic_store(&tb[(((iter + 2) & 3) << 10) + r0 + t], 0.0f,
                               __ATOMIC_RELAXED, __HIP_MEMORY_SCOPE_AGENT);
        __syncthreads();   // vmcnt(0)+lgkmcnt(0): atomics drained, part zeroed

        // ---- single LLC barrier per iteration ----
        tgt += 16;
        if (t == 0) {
            __hip_atomic_fetch_add(flag, 1u, __ATOMIC_RELAXED, __HIP_MEMORY_SCOPE_AGENT);
            while (__hip_atomic_load(flag, __ATOMIC_RELAXED, __HIP_MEMORY_SCOPE_AGENT) < tgt)
                __builtin_amdgcn_s_sleep(2);
        }
        __syncthreads();

        // ---- read t (LLC), compute v, store swizzled ----
        float t0 = __hip_atomic_load(&tcur[c0],     __ATOMIC_RELAXED, __HIP_MEMORY_SCOPE_AGENT);
        float t1 = __hip_atomic_load(&tcur[c0 + 1], __ATOMIC_RELAXED, __HIP_MEMORY_SCOPE_AGENT);
        int c1 = c0 + 1;
        vsw[((c0 & 15) << 6) + (c0 >> 4)] = (1.0f / 1024.0f) / t0;
        vsw[((c1 & 15) << 6) + (c1 >> 4)] = (1.0f / 1024.0f) / t1;
        __syncthreads();
    }

    // ---- fused loss over strip: sum_ij u_i K_ij v_j * (-eps ln K_ij) ----
    {
        float vreg[16];
        #pragma unroll
        for (int k = 0; k < 16; k++) vreg[k] = vsw[((k ^ sw8) << 6) + lane];
        float wsum = 0.f;
        #pragma unroll
        for (int rr = 0; rr < 8; rr++) {
            const char* kr = ksb + (((w << 3) + rr) << 11);
            uint4 A = *(const uint4*)(kr + xa);
            uint4 B = *(const uint4*)(kr + xb);
            float f[16]; UNPK(A, B, f);
            float s = 0.f;
            #pragma unroll
            for (int k = 0; k < 16; k++) {
                float c = -EPS_F * __logf(f[k]);
                s = fmaf(f[k] * vreg[k], c, s);
            }
            #pragma unroll
            for (int m = 32; m; m >>= 1) s += __shfl_xor(s, m, 64);
            if (lane == 0) wsum += s * ulds[(w << 3) + rr];
        }
        if (lane == 0) wlds[w] = wsum;
    }
    __syncthreads();
    if (t == 0) {
        float s = 0.f;
        #pragma unroll
        for (int g = 0; g < 8; g++) s += wlds[g];
        partials[idx] = s;
    }
}

// ---------------- final reduce ----------------
__global__ __launch_bounds__(256) void loss_final(
    const float* __restrict__ partials, float* __restrict__ out)
{
    int t = threadIdx.x;
    float s = partials[t];
    #pragma unroll
    for (int m = 32; m; m >>= 1) s += __shfl_xor(s, m, 64);
    __shared__ float wp[4];
    if ((t & 63) == 0) wp[t >> 6] = s;
    __syncthreads();
    if (t == 0) out[0] = (wp[0] + wp[1] + wp[2] + wp[3]) * (1.0f / 16.0f);
}

extern "C" void kernel_launch(void* const* d_in, const int* in_sizes, int n_in,
                              void* d_out, int out_size, void* d_ws, size_t ws_size,
                              hipStream_t stream) {
    const float* student = (const float*)d_in[0];
    const float* teacher = (const float*)d_in[1];
    float* out = (float*)d_out;
    char* ws = (char*)d_ws;

    unsigned short* Tn   = (unsigned short*)(ws);                     // 64 MB
    unsigned short* Sn   = (unsigned short*)(ws + 67108864);          // 64 MB
    unsigned short* Kmat = (unsigned short*)(ws + 134217728);         // 32 MB
    float*        tbuf     = (float*)(ws + 167772160);                // 256 KB
    unsigned int* flags    = (unsigned int*)(ws + 167772160 + 262144);// 4 KB
    float*        partials = (float*)(ws + 167772160 + 266240);       // 1 KB

    hipLaunchKernelGGL(init_state, dim3(64), dim3(256), 0, stream, tbuf, flags);
    hipLaunchKernelGGL(normalize_kernel, dim3(32768), dim3(256), 0, stream,
                       student, teacher, Sn, Tn);
    hipLaunchKernelGGL(gemm_cost_kernel, dim3(1024), dim3(256), 0, stream, Tn, Sn, Kmat);
    hipLaunchKernelGGL(sinkhorn_persistent, dim3(256), dim3(512), 0, stream,
                       Kmat, tbuf, flags, partials);
    hipLaunchKernelGGL(loss_final, dim3(1), dim3(256), 0, stream, partials, out);
}

// Round 2
// 1843.020 us; speedup vs baseline: 1.0019x; 1.0019x over previous
//
#include <hip/hip_runtime.h>
#include <math.h>

#define BATCH 16
#define SEQ   1024
#define DIM   2048
#define EPS_F 0.1f
#define INV_EPS 10.0f
#define N_ITER 100

typedef short bf16x8 __attribute__((ext_vector_type(8)));
typedef float f32x4  __attribute__((ext_vector_type(4)));

__device__ inline float blo(unsigned int x) { return __uint_as_float(x << 16); }
__device__ inline float bhi(unsigned int x) { return __uint_as_float(x & 0xffff0000u); }

__device__ inline unsigned short f_to_bf16(float f) {
    unsigned int x = __float_as_uint(f);
    unsigned int lsb = (x >> 16) & 1u;
    x += 0x7fffu + lsb;               // round-to-nearest-even
    return (unsigned short)(x >> 16);
}

// ---------------- init: t buffers = 0, flags = 0 ----------------
__global__ void init_state(float* __restrict__ tbuf, unsigned int* __restrict__ flags) {
    int i = blockIdx.x * 256 + threadIdx.x;   // grid 64*256 = 16384
    ((float4*)tbuf)[i] = (float4){0.f, 0.f, 0.f, 0.f};
    if (i < 1024) flags[i] = 0u;
}

// ---------------- normalize + cast to bf16 ----------------
__global__ __launch_bounds__(256) void normalize_kernel(
    const float* __restrict__ student, const float* __restrict__ teacher,
    unsigned short* __restrict__ Sn, unsigned short* __restrict__ Tn)
{
    int rowid  = blockIdx.x;
    int tensor = rowid >> 14;
    int row    = rowid & 16383;
    const float* src = tensor ? teacher : student;
    unsigned short* dst = tensor ? Tn : Sn;
    const float4* p4 = (const float4*)(src + (size_t)row * DIM);
    int t = threadIdx.x;

    float4 a = p4[t];
    float4 b = p4[t + 256];
    float ss = a.x*a.x + a.y*a.y + a.z*a.z + a.w*a.w
             + b.x*b.x + b.y*b.y + b.z*b.z + b.w*b.w;
    #pragma unroll
    for (int m = 32; m; m >>= 1) ss += __shfl_xor(ss, m, 64);
    __shared__ float wss[4];
    if ((t & 63) == 0) wss[t >> 6] = ss;
    __syncthreads();
    float rn = 1.0f / fmaxf(sqrtf(wss[0] + wss[1] + wss[2] + wss[3]), 1e-12f);

    unsigned short o1[4], o2[4];
    o1[0] = f_to_bf16(a.x * rn); o1[1] = f_to_bf16(a.y * rn);
    o1[2] = f_to_bf16(a.z * rn); o1[3] = f_to_bf16(a.w * rn);
    o2[0] = f_to_bf16(b.x * rn); o2[1] = f_to_bf16(b.y * rn);
    o2[2] = f_to_bf16(b.z * rn); o2[3] = f_to_bf16(b.w * rn);
    unsigned short* d = dst + (size_t)row * DIM;
    *(uint2*)(d + 4*t)        = *(uint2*)o1;
    *(uint2*)(d + 1024 + 4*t) = *(uint2*)o2;
}

// ---------------- batched GEMM -> K = exp(-C/eps), bf16 ----------------
#define TM  128
#define BK  32
#define LDK 40

__global__ __launch_bounds__(256) void gemm_cost_kernel(
    const unsigned short* __restrict__ Tn, const unsigned short* __restrict__ Sn,
    unsigned short* __restrict__ Kmat)
{
    __shared__ unsigned short As[TM * LDK];
    __shared__ unsigned short Bs[TM * LDK];

    int bid  = blockIdx.x;
    int b    = bid >> 6;
    int tile = bid & 63;
    int tm0  = (tile >> 3) * TM;
    int tn0  = (tile & 7)  * TM;

    const unsigned short* Ab = Tn + (size_t)b * SEQ * DIM;
    const unsigned short* Bb = Sn + (size_t)b * SEQ * DIM;

    int t    = threadIdx.x;
    int w    = t >> 6;
    int l    = t & 63;
    int mq   = (w >> 1) * 64;
    int nq   = (w & 1)  * 64;
    int lrow = l & 15;
    int kg   = l >> 4;

    int srow = t >> 2;
    int sseg = t & 3;

    f32x4 acc[4][4];
    #pragma unroll
    for (int i = 0; i < 4; i++)
        #pragma unroll
        for (int j = 0; j < 4; j++)
            acc[i][j] = (f32x4){0.f, 0.f, 0.f, 0.f};

    for (int k0 = 0; k0 < DIM; k0 += BK) {
        const int4 va0 = *(const int4*)(Ab + (size_t)(tm0 + srow)      * DIM + k0 + sseg * 8);
        const int4 va1 = *(const int4*)(Ab + (size_t)(tm0 + srow + 64) * DIM + k0 + sseg * 8);
        const int4 vb0 = *(const int4*)(Bb + (size_t)(tn0 + srow)      * DIM + k0 + sseg * 8);
        const int4 vb1 = *(const int4*)(Bb + (size_t)(tn0 + srow + 64) * DIM + k0 + sseg * 8);
        __syncthreads();
        *(int4*)&As[(srow)      * LDK + sseg * 8] = va0;
        *(int4*)&As[(srow + 64) * LDK + sseg * 8] = va1;
        *(int4*)&Bs[(srow)      * LDK + sseg * 8] = vb0;
        *(int4*)&Bs[(srow + 64) * LDK + sseg * 8] = vb1;
        __syncthreads();

        bf16x8 af[4], bfr[4];
        #pragma unroll
        for (int i = 0; i < 4; i++)
            af[i] = *(const bf16x8*)&As[(mq + i * 16 + lrow) * LDK + kg * 8];
        #pragma unroll
        for (int j = 0; j < 4; j++)
            bfr[j] = *(const bf16x8*)&Bs[(nq + j * 16 + lrow) * LDK + kg * 8];
        #pragma unroll
        for (int i = 0; i < 4; i++)
            #pragma unroll
            for (int j = 0; j < 4; j++)
                acc[i][j] = __builtin_amdgcn_mfma_f32_16x16x32_bf16(af[i], bfr[j], acc[i][j], 0, 0, 0);
    }

    unsigned short* Kb = Kmat + ((size_t)b << 20);
    #pragma unroll
    for (int i = 0; i < 4; i++) {
        #pragma unroll
        for (int j = 0; j < 4; j++) {
            int gcol = tn0 + nq + j * 16 + lrow;
            #pragma unroll
            for (int r = 0; r < 4; r++) {
                int grow = tm0 + mq + i * 16 + kg * 4 + r;
                float cosv = acc[i][j][r];
                float cost = 0.5f - 0.5f * cosv;
                Kb[((size_t)grow << 10) + gcol] = f_to_bf16(__expf(-cost * INV_EPS));
            }
        }
    }
}

// ---------------- persistent Sinkhorn + fused loss ----------------
// 256 blocks x 512 threads. Block owns a 64-row strip of one batch.
// Round-2 fixes vs round-1 (which fell onto the flat path):
//   * ALL K-strip LDS accesses use the proven element-indexed idiom
//     *(const uint4*)&Ks[row*1024 + e]  -> guaranteed ds_read_b128
//     (round-1's (char*)Ks + byte XOR math broke addrspace inference:
//      SGPR 32->112, VALUBusy 28->12%, 3x regression).
//   * part[] uses the v-swizzle layout part[j*64+lane]: each of the 16
//     ds_add_f32 instructions hits banks lane%32 (2-way = free), instead
//     of the stride-16 layout that kept 8-way conflicts.
// Structure otherwise identical to round-1 (LDS-resident K, 4-row batched
// butterflies, single LLC barrier per iteration).
#define UNPK(A,B,F) do { \
    F[0]=blo(A.x);  F[1]=bhi(A.x);  F[2]=blo(A.y);  F[3]=bhi(A.y);  \
    F[4]=blo(A.z);  F[5]=bhi(A.z);  F[6]=blo(A.w);  F[7]=bhi(A.w);  \
    F[8]=blo(B.x);  F[9]=bhi(B.x);  F[10]=blo(B.y); F[11]=bhi(B.y); \
    F[12]=blo(B.z); F[13]=bhi(B.z); F[14]=blo(B.w); F[15]=bhi(B.w); } while(0)

__global__ __launch_bounds__(512, 2) void sinkhorn_persistent(
    const unsigned short* __restrict__ Kmat,
    float* __restrict__ tbuf,          // [16][4][1024]
    unsigned int* __restrict__ flags,  // [16][64]
    float* __restrict__ partials)      // [256]
{
    __shared__ __align__(16) unsigned short Ks[64 * 1024]; // 128 KB K strip
    __shared__ float vsw[1024];        // v, swizzled: v[c] at (c&15)*64 + (c>>4)
    __shared__ float part[1024];       // column partials, SAME swizzled layout
    __shared__ float ulds[64];
    __shared__ float wlds[8];

    int idx   = blockIdx.x;
    int b     = (idx & 7) | (((idx >> 3) & 1) << 3);  // idx%8 == b%8 : XCD-pinned
    int slice = idx >> 4;                             // 0..15
    const unsigned short* Kb = Kmat + ((size_t)b << 20);
    float* tb = tbuf + (b << 12);
    unsigned int* flag = flags + b * 64;

    int t    = threadIdx.x;
    int lane = t & 63;
    int w    = t >> 6;                 // wave 0..7
    int r0   = slice << 6;             // this block's 64 rows (also its 64-col zero-slice)

    // lane reads its 16 columns as two 8-col uint4 halves; sw swaps the
    // halves for odd lane-quads so the b128 reads cover all 32 banks.
    // Register k holds logical column offset j = k ^ sw8.
    int sw8 = ((lane >> 2) & 1) << 3;
    int ea  = (lane << 4) ^ sw8;       // element offset of half A within row
    int eb  = ea ^ 8;                  // element offset of half B

    // ---- one-time: preload K strip (contiguous 128 KB) + init ----
    {
        const int4* src = (const int4*)(Kb + ((size_t)r0 << 10));
        #pragma unroll
        for (int i = 0; i < 16; i++)
            *(int4*)&Ks[(size_t)(t + i * 512) << 3] = src[t + i * 512];
    }
    vsw[t] = 1.0f; vsw[t + 512] = 1.0f;     // v0 = 1 (swizzle of ones is ones)
    part[t] = 0.f; part[t + 512] = 0.f;
    __syncthreads();

    unsigned int tgt = 0;
    for (int iter = 0; iter < N_ITER; iter++) {
        // vreg[k] = v[lane*16 + (k^sw8)] — runtime address, static reg index
        float vreg[16];
        #pragma unroll
        for (int k = 0; k < 16; k++) vreg[k] = vsw[((k ^ sw8) << 6) + lane];

        float tacc[16];
        #pragma unroll
        for (int k = 0; k < 16; k++) tacc[k] = 0.f;

        // ---- sweep: 2 batches of 4 rows, butterflies interleaved ----
        #pragma unroll
        for (int bb = 0; bb < 2; bb++) {
            int rb = ((w << 3) + (bb << 2)) << 10;   // element index of batch row 0
            uint4 a0 = *(const uint4*)&Ks[rb          + ea];
            uint4 b0 = *(const uint4*)&Ks[rb          + eb];
            uint4 a1 = *(const uint4*)&Ks[rb + 1024   + ea];
            uint4 b1 = *(const uint4*)&Ks[rb + 1024   + eb];
            uint4 a2 = *(const uint4*)&Ks[rb + 2048   + ea];
            uint4 b2 = *(const uint4*)&Ks[rb + 2048   + eb];
            uint4 a3 = *(const uint4*)&Ks[rb + 3072   + ea];
            uint4 b3 = *(const uint4*)&Ks[rb + 3072   + eb];
            float f0[16], f1[16], f2[16], f3[16];
            UNPK(a0, b0, f0); UNPK(a1, b1, f1);
            UNPK(a2, b2, f2); UNPK(a3, b3, f3);

            float s0 = 0.f, s1 = 0.f, s2 = 0.f, s3 = 0.f;
            #pragma unroll
            for (int k = 0; k < 16; k++) {
                s0 = fmaf(f0[k], vreg[k], s0);
                s1 = fmaf(f1[k], vreg[k], s1);
                s2 = fmaf(f2[k], vreg[k], s2);
                s3 = fmaf(f3[k], vreg[k], s3);
            }
            #pragma unroll
            for (int m = 32; m; m >>= 1) {   // 4 independent chains, pipelined
                s0 += __shfl_xor(s0, m, 64);
                s1 += __shfl_xor(s1, m, 64);
                s2 += __shfl_xor(s2, m, 64);
                s3 += __shfl_xor(s3, m, 64);
            }
            float u0 = (1.0f / 1024.0f) / s0;
            float u1 = (1.0f / 1024.0f) / s1;
            float u2 = (1.0f / 1024.0f) / s2;
            float u3 = (1.0f / 1024.0f) / s3;
            if (lane == 0) {
                int rr = (w << 3) + (bb << 2);
                ulds[rr] = u0; ulds[rr + 1] = u1; ulds[rr + 2] = u2; ulds[rr + 3] = u3;
            }
            #pragma unroll
            for (int k = 0; k < 16; k++) {
                tacc[k] = fmaf(f0[k], u0, tacc[k]);
                tacc[k] = fmaf(f1[k], u1, tacc[k]);
                tacc[k] = fmaf(f2[k], u2, tacc[k]);
                tacc[k] = fmaf(f3[k], u3, tacc[k]);
            }
        }
        // wave partials -> shared column sums.
        // col c = lane*16 + j (j = k^sw8) stored at part[j*64+lane]:
        // per instruction, banks = lane%32 -> 2-way aliasing = free.
        #pragma unroll
        for (int k = 0; k < 16; k++)
            atomicAdd(&part[((k ^ sw8) << 6) + lane], tacc[k]);
        __syncthreads();

        // per-thread cols 2t,2t+1 -> LLC atomics; re-zero part for next iter
        int cur = iter & 3;
        float* tcur = tb + (cur << 10);
        int c0 = t * 2, c1 = t * 2 + 1;
        int i0 = ((c0 & 15) << 6) + (c0 >> 4);
        int i1 = ((c1 & 15) << 6) + (c1 >> 4);
        float p0 = part[i0];
        float p1 = part[i1];
        atomicAdd(&tcur[c0], p0);
        atomicAdd(&tcur[c1], p1);
        part[i0] = 0.f;
        part[i1] = 0.f;
        if (t < 64)
            __hip_atomic_store(&tb[(((iter + 2) & 3) << 10) + r0 + t], 0.0f,
                               __ATOMIC_RELAXED, __HIP_MEMORY_SCOPE_AGENT);
        __syncthreads();   // vmcnt(0)+lgkmcnt(0): atomics drained, part zeroed

        // ---- single LLC barrier per iteration ----
        tgt += 16;
        if (t == 0) {
            __hip_atomic_fetch_add(flag, 1u, __ATOMIC_RELAXED, __HIP_MEMORY_SCOPE_AGENT);
            while (__hip_atomic_load(flag, __ATOMIC_RELAXED, __HIP_MEMORY_SCOPE_AGENT) < tgt)
                __builtin_amdgcn_s_sleep(2);
        }
        __syncthreads();

        // ---- read t (LLC), compute v, store swizzled ----
        float t0 = __hip_atomic_load(&tcur[c0], __ATOMIC_RELAXED, __HIP_MEMORY_SCOPE_AGENT);
        float t1 = __hip_atomic_load(&tcur[c1], __ATOMIC_RELAXED, __HIP_MEMORY_SCOPE_AGENT);
        vsw[i0] = (1.0f / 1024.0f) / t0;
        vsw[i1] = (1.0f / 1024.0f) / t1;
        __syncthreads();
    }

    // ---- fused loss over strip: sum_ij u_i K_ij v_j * (-eps ln K_ij) ----
    {
        float vreg[16];
        #pragma unroll
        for (int k = 0; k < 16; k++) vreg[k] = vsw[((k ^ sw8) << 6) + lane];
        float wsum = 0.f;
        #pragma unroll
        for (int rr = 0; rr < 8; rr++) {
            int rb = ((w << 3) + rr) << 10;
            uint4 A = *(const uint4*)&Ks[rb + ea];
            uint4 B = *(const uint4*)&Ks[rb + eb];
            float f[16]; UNPK(A, B, f);
            float s = 0.f;
            #pragma unroll
            for (int k = 0; k < 16; k++) {
                float c = -EPS_F * __logf(f[k]);
                s = fmaf(f[k] * vreg[k], c, s);
            }
            #pragma unroll
            for (int m = 32; m; m >>= 1) s += __shfl_xor(s, m, 64);
            if (lane == 0) wsum += s * ulds[(w << 3) + rr];
        }
        if (lane == 0) wlds[w] = wsum;
    }
    __syncthreads();
    if (t == 0) {
        float s = 0.f;
        #pragma unroll
        for (int g = 0; g < 8; g++) s += wlds[g];
        partials[idx] = s;
    }
}

// ---------------- final reduce ----------------
__global__ __launch_bounds__(256) void loss_final(
    const float* __restrict__ partials, float* __restrict__ out)
{
    int t = threadIdx.x;
    float s = partials[t];
    #pragma unroll
    for (int m = 32; m; m >>= 1) s += __shfl_xor(s, m, 64);
    __shared__ float wp[4];
    if ((t & 63) == 0) wp[t >> 6] = s;
    __syncthreads();
    if (t == 0) out[0] = (wp[0] + wp[1] + wp[2] + wp[3]) * (1.0f / 16.0f);
}

extern "C" void kernel_launch(void* const* d_in, const int* in_sizes, int n_in,
                              void* d_out, int out_size, void* d_ws, size_t ws_size,
                              hipStream_t stream) {
    const float* student = (const float*)d_in[0];
    const float* teacher = (const float*)d_in[1];
    float* out = (float*)d_out;
    char* ws = (char*)d_ws;

    unsigned short* Tn   = (unsigned short*)(ws);                     // 64 MB
    unsigned short* Sn   = (unsigned short*)(ws + 67108864);          // 64 MB
    unsigned short* Kmat = (unsigned short*)(ws + 134217728);         // 32 MB
    float*        tbuf     = (float*)(ws + 167772160);                // 256 KB
    unsigned int* flags    = (unsigned int*)(ws + 167772160 + 262144);// 4 KB
    float*        partials = (float*)(ws + 167772160 + 266240);       // 1 KB

    hipLaunchKernelGGL(init_state, dim3(64), dim3(256), 0, stream, tbuf, flags);
    hipLaunchKernelGGL(normalize_kernel, dim3(32768), dim3(256), 0, stream,
                       student, teacher, Sn, Tn);
    hipLaunchKernelGGL(gemm_cost_kernel, dim3(1024), dim3(256), 0, stream, Tn, Sn, Kmat);
    hipLaunchKernelGGL(sinkhorn_persistent, dim3(256), dim3(512), 0, stream,
                       Kmat, tbuf, flags, partials);
    hipLaunchKernelGGL(loss_final, dim3(1), dim3(256), 0, stream, partials, out);
}

// Round 3
// 873.202 us; speedup vs baseline: 2.1147x; 2.1106x over previous
//
#include <hip/hip_runtime.h>
#include <math.h>

#define BATCH 16
#define SEQ   1024
#define DIM   2048
#define EPS_F 0.1f
#define INV_EPS 10.0f
#define N_ITER 100

typedef short bf16x8 __attribute__((ext_vector_type(8)));
typedef float f32x4  __attribute__((ext_vector_type(4)));

__device__ inline float blo(unsigned int x) { return __uint_as_float(x << 16); }
__device__ inline float bhi(unsigned int x) { return __uint_as_float(x & 0xffff0000u); }

__device__ inline unsigned short f_to_bf16(float f) {
    unsigned int x = __float_as_uint(f);
    unsigned int lsb = (x >> 16) & 1u;
    x += 0x7fffu + lsb;               // round-to-nearest-even
    return (unsigned short)(x >> 16);
}

// async global->LDS, 16B per lane; LDS dest is wave-uniform base + lane*16
__device__ __forceinline__ void gload16(const void* g, void* l) {
    __builtin_amdgcn_global_load_lds(
        (const __attribute__((address_space(1))) void*)g,
        (__attribute__((address_space(3))) void*)l, 16, 0, 0);
}

// ---------------- init: t buffers = 0, flags = 0 ----------------
__global__ void init_state(float* __restrict__ tbuf, unsigned int* __restrict__ flags) {
    int i = blockIdx.x * 256 + threadIdx.x;   // grid 64*256 = 16384
    ((float4*)tbuf)[i] = (float4){0.f, 0.f, 0.f, 0.f};
    if (i < 1024) flags[i] = 0u;
}

// ---------------- normalize + cast to bf16 ----------------
__global__ __launch_bounds__(256) void normalize_kernel(
    const float* __restrict__ student, const float* __restrict__ teacher,
    unsigned short* __restrict__ Sn, unsigned short* __restrict__ Tn)
{
    int rowid  = blockIdx.x;
    int tensor = rowid >> 14;
    int row    = rowid & 16383;
    const float* src = tensor ? teacher : student;
    unsigned short* dst = tensor ? Tn : Sn;
    const float4* p4 = (const float4*)(src + (size_t)row * DIM);
    int t = threadIdx.x;

    float4 a = p4[t];
    float4 b = p4[t + 256];
    float ss = a.x*a.x + a.y*a.y + a.z*a.z + a.w*a.w
             + b.x*b.x + b.y*b.y + b.z*b.z + b.w*b.w;
    #pragma unroll
    for (int m = 32; m; m >>= 1) ss += __shfl_xor(ss, m, 64);
    __shared__ float wss[4];
    if ((t & 63) == 0) wss[t >> 6] = ss;
    __syncthreads();
    float rn = 1.0f / fmaxf(sqrtf(wss[0] + wss[1] + wss[2] + wss[3]), 1e-12f);

    unsigned short o1[4], o2[4];
    o1[0] = f_to_bf16(a.x * rn); o1[1] = f_to_bf16(a.y * rn);
    o1[2] = f_to_bf16(a.z * rn); o1[3] = f_to_bf16(a.w * rn);
    o2[0] = f_to_bf16(b.x * rn); o2[1] = f_to_bf16(b.y * rn);
    o2[2] = f_to_bf16(b.z * rn); o2[3] = f_to_bf16(b.w * rn);
    unsigned short* d = dst + (size_t)row * DIM;
    *(uint2*)(d + 4*t)        = *(uint2*)o1;
    *(uint2*)(d + 1024 + 4*t) = *(uint2*)o2;
}

// ---------------- batched GEMM -> K = exp(-C/eps), bf16 ----------------
// Round-3: global_load_lds width-16 staging into LINEAR [128][32] LDS tiles
// (m93->m97 ladder step, +69% measured). Each 16-row x 64B tile slab is a
// contiguous 1KB chunk == one wave-uniform-base + lane*16B instruction.
// 4 waves x (2 A-chunks + 2 B-chunks) per K-step. 16 KB LDS total.
#define TM  128

__global__ __launch_bounds__(256) void gemm_cost_kernel(
    const unsigned short* __restrict__ Tn, const unsigned short* __restrict__ Sn,
    unsigned short* __restrict__ Kmat)
{
    __shared__ __align__(16) unsigned short As[TM * 32];   // 8 KB, linear
    __shared__ __align__(16) unsigned short Bs[TM * 32];   // 8 KB, linear

    int bid  = blockIdx.x;
    int b    = bid >> 6;
    int tile = bid & 63;
    int tm0  = (tile >> 3) * TM;
    int tn0  = (tile & 7)  * TM;

    const unsigned short* Ab = Tn + (size_t)b * SEQ * DIM;
    const unsigned short* Bb = Sn + (size_t)b * SEQ * DIM;

    int t    = threadIdx.x;
    int w    = t >> 6;
    int l    = t & 63;
    int mq   = (w >> 1) * 64;
    int nq   = (w & 1)  * 64;
    int lrow = l & 15;
    int kg   = l >> 4;

    // staging: wave w owns rows [32w, 32w+32) of A and of B.
    // chunk (16 rows = 1KB): lane l -> row 32w + l/4, col-bytes (l&3)*16.
    const unsigned short* gA0 = Ab + (size_t)(tm0 + (w << 5) + (l >> 2)) * DIM + ((l & 3) << 3);
    const unsigned short* gA1 = gA0 + (size_t)16 * DIM;
    const unsigned short* gB0 = Bb + (size_t)(tn0 + (w << 5) + (l >> 2)) * DIM + ((l & 3) << 3);
    const unsigned short* gB1 = gB0 + (size_t)16 * DIM;
    unsigned short* lA0 = &As[(w << 10)];         // shorts: chunk 2w   at w*1024
    unsigned short* lA1 = &As[(w << 10) + 512];   //         chunk 2w+1
    unsigned short* lB0 = &Bs[(w << 10)];
    unsigned short* lB1 = &Bs[(w << 10) + 512];

    f32x4 acc[4][4];
    #pragma unroll
    for (int i = 0; i < 4; i++)
        #pragma unroll
        for (int j = 0; j < 4; j++)
            acc[i][j] = (f32x4){0.f, 0.f, 0.f, 0.f};

    for (int k0 = 0; k0 < DIM; k0 += 32) {
        __syncthreads();               // previous iter's ds_reads complete
        gload16(gA0 + k0, lA0);
        gload16(gA1 + k0, lA1);
        gload16(gB0 + k0, lB0);
        gload16(gB1 + k0, lB1);
        __syncthreads();               // vmcnt(0) drained before barrier -> tile ready

        bf16x8 af[4], bfr[4];
        #pragma unroll
        for (int i = 0; i < 4; i++)
            af[i] = *(const bf16x8*)&As[(mq + i * 16 + lrow) * 32 + kg * 8];
        #pragma unroll
        for (int j = 0; j < 4; j++)
            bfr[j] = *(const bf16x8*)&Bs[(nq + j * 16 + lrow) * 32 + kg * 8];
        #pragma unroll
        for (int i = 0; i < 4; i++)
            #pragma unroll
            for (int j = 0; j < 4; j++)
                acc[i][j] = __builtin_amdgcn_mfma_f32_16x16x32_bf16(af[i], bfr[j], acc[i][j], 0, 0, 0);
    }

    unsigned short* Kb = Kmat + ((size_t)b << 20);
    #pragma unroll
    for (int i = 0; i < 4; i++) {
        #pragma unroll
        for (int j = 0; j < 4; j++) {
            int gcol = tn0 + nq + j * 16 + lrow;
            #pragma unroll
            for (int r = 0; r < 4; r++) {
                int grow = tm0 + mq + i * 16 + kg * 4 + r;
                float cosv = acc[i][j][r];
                float cost = 0.5f - 0.5f * cosv;
                Kb[((size_t)grow << 10) + gcol] = f_to_bf16(__expf(-cost * INV_EPS));
            }
        }
    }
}

// ---------------- persistent Sinkhorn + fused loss ----------------
// VERBATIM round-0 version (measured 483 us standalone). Rounds 1-2 moved K
// into LDS + used ds_add_f32 for the cross-wave reduce: 3x regression. The
// K reads belong on the VMEM pipe (L2-resident strip) running in parallel
// with the LDS pipe (shfl butterflies + plain-write partials).
__global__ __launch_bounds__(512) void sinkhorn_persistent(
    const unsigned short* __restrict__ Kmat,
    float* __restrict__ tbuf,          // [16][4][1024]
    unsigned int* __restrict__ flags,  // [16][64]
    float* __restrict__ partials)      // [256]
{
    __shared__ float part[8 * 1024];   // per-wave column partials
    __shared__ float vsw[1024];        // v, swizzled: v[c] at (c&15)*64 + (c>>4)
    __shared__ float ulds[64];
    __shared__ float wlds[8];

    int idx   = blockIdx.x;
    int b     = (idx & 7) | (((idx >> 3) & 1) << 3);  // idx%8 == b%8 : XCD-pinned
    int slice = idx >> 4;                             // 0..15
    const unsigned short* Kb = Kmat + ((size_t)b << 20);
    float* tb = tbuf + (b << 12);
    unsigned int* flag = flags + b * 64;

    int t    = threadIdx.x;
    int lane = t & 63;
    int w    = t >> 6;                 // wave 0..7
    int r0   = slice << 6;             // this block's 64 rows (also its 64-col zero-slice)

    vsw[t] = 1.0f; vsw[t + 512] = 1.0f;     // v0 = 1 (swizzle of ones is ones)
    __syncthreads();

    unsigned int tgt = 0;
    for (int iter = 0; iter < N_ITER; iter++) {
        // vreg[k] = v[lane*16 + k]  — conflict-free swizzled loads
        float vreg[16];
        #pragma unroll
        for (int k = 0; k < 16; k++) vreg[k] = vsw[k * 64 + lane];

        float tacc[16];
        #pragma unroll
        for (int k = 0; k < 16; k++) tacc[k] = 0.f;

        // ---- fused sweep over 8 rows: u_i then column partials ----
        #pragma unroll
        for (int rr = 0; rr < 8; rr++) {
            int row = r0 + w * 8 + rr;
            const unsigned int* kp = (const unsigned int*)(Kb + ((size_t)row << 10) + (lane << 4));
            unsigned int k0 = kp[0], k1 = kp[1], k2 = kp[2], k3 = kp[3];
            unsigned int k4 = kp[4], k5 = kp[5], k6 = kp[6], k7 = kp[7];
            float f0  = blo(k0), f1  = bhi(k0), f2  = blo(k1), f3  = bhi(k1);
            float f4  = blo(k2), f5  = bhi(k2), f6  = blo(k3), f7  = bhi(k3);
            float f8  = blo(k4), f9  = bhi(k4), f10 = blo(k5), f11 = bhi(k5);
            float f12 = blo(k6), f13 = bhi(k6), f14 = blo(k7), f15 = bhi(k7);
            float s = 0.f;
            s = fmaf(f0,  vreg[0],  s); s = fmaf(f1,  vreg[1],  s);
            s = fmaf(f2,  vreg[2],  s); s = fmaf(f3,  vreg[3],  s);
            s = fmaf(f4,  vreg[4],  s); s = fmaf(f5,  vreg[5],  s);
            s = fmaf(f6,  vreg[6],  s); s = fmaf(f7,  vreg[7],  s);
            s = fmaf(f8,  vreg[8],  s); s = fmaf(f9,  vreg[9],  s);
            s = fmaf(f10, vreg[10], s); s = fmaf(f11, vreg[11], s);
            s = fmaf(f12, vreg[12], s); s = fmaf(f13, vreg[13], s);
            s = fmaf(f14, vreg[14], s); s = fmaf(f15, vreg[15], s);
            #pragma unroll
            for (int m = 32; m; m >>= 1) s += __shfl_xor(s, m, 64);
            float ui = (1.0f / 1024.0f) / s;          // uniform across wave
            if (lane == 0) ulds[w * 8 + rr] = ui;
            tacc[0]  = fmaf(f0,  ui, tacc[0]);  tacc[1]  = fmaf(f1,  ui, tacc[1]);
            tacc[2]  = fmaf(f2,  ui, tacc[2]);  tacc[3]  = fmaf(f3,  ui, tacc[3]);
            tacc[4]  = fmaf(f4,  ui, tacc[4]);  tacc[5]  = fmaf(f5,  ui, tacc[5]);
            tacc[6]  = fmaf(f6,  ui, tacc[6]);  tacc[7]  = fmaf(f7,  ui, tacc[7]);
            tacc[8]  = fmaf(f8,  ui, tacc[8]);  tacc[9]  = fmaf(f9,  ui, tacc[9]);
            tacc[10] = fmaf(f10, ui, tacc[10]); tacc[11] = fmaf(f11, ui, tacc[11]);
            tacc[12] = fmaf(f12, ui, tacc[12]); tacc[13] = fmaf(f13, ui, tacc[13]);
            tacc[14] = fmaf(f14, ui, tacc[14]); tacc[15] = fmaf(f15, ui, tacc[15]);
        }
        // wave partials -> LDS
        #pragma unroll
        for (int k = 0; k < 16; k += 4)
            *(float4*)&part[w * 1024 + lane * 16 + k] =
                (float4){tacc[k], tacc[k+1], tacc[k+2], tacc[k+3]};
        __syncthreads();

        // reduce 8 waves, then LLC atomics (cols 2t, 2t+1)
        float a0 = 0.f, a1 = 0.f;
        #pragma unroll
        for (int g = 0; g < 8; g++) {
            float2 p = *(const float2*)&part[g * 1024 + t * 2];
            a0 += p.x; a1 += p.y;
        }
        int cur = iter & 3;
        float* tcur = tb + (cur << 10);
        atomicAdd(&tcur[t * 2],     a0);
        atomicAdd(&tcur[t * 2 + 1], a1);
        if (t < 64)
            __hip_atomic_store(&tb[(((iter + 2) & 3) << 10) + r0 + t], 0.0f,
                               __ATOMIC_RELAXED, __HIP_MEMORY_SCOPE_AGENT);
        __syncthreads();   // per-wave vmcnt(0): all atomics drained to LLC

        // ---- single LLC barrier per iteration ----
        tgt += 16;
        if (t == 0) {
            __hip_atomic_fetch_add(flag, 1u, __ATOMIC_RELAXED, __HIP_MEMORY_SCOPE_AGENT);
            while (__hip_atomic_load(flag, __ATOMIC_RELAXED, __HIP_MEMORY_SCOPE_AGENT) < tgt)
                __builtin_amdgcn_s_sleep(2);
        }
        __syncthreads();

        // ---- read t (LLC), compute v, store swizzled ----
        float t0 = __hip_atomic_load(&tcur[t * 2],     __ATOMIC_RELAXED, __HIP_MEMORY_SCOPE_AGENT);
        float t1 = __hip_atomic_load(&tcur[t * 2 + 1], __ATOMIC_RELAXED, __HIP_MEMORY_SCOPE_AGENT);
        int c0 = t * 2, c1 = t * 2 + 1;
        vsw[(c0 & 15) * 64 + (c0 >> 4)] = (1.0f / 1024.0f) / t0;
        vsw[(c1 & 15) * 64 + (c1 >> 4)] = (1.0f / 1024.0f) / t1;
        __syncthreads();
    }

    // ---- fused loss over strip: sum_ij u_i K_ij v_j * (-eps ln K_ij) ----
    {
        float vreg[16];
        #pragma unroll
        for (int k = 0; k < 16; k++) vreg[k] = vsw[k * 64 + lane];
        float wsum = 0.f;
        #pragma unroll
        for (int rr = 0; rr < 8; rr++) {
            int row = r0 + w * 8 + rr;
            const unsigned int* kp = (const unsigned int*)(Kb + ((size_t)row << 10) + (lane << 4));
            float s = 0.f;
            #pragma unroll
            for (int q = 0; q < 8; q++) {
                unsigned int kk = kp[q];
                float klo = blo(kk), khi = bhi(kk);
                float clo = -EPS_F * __logf(klo);
                float chi = -EPS_F * __logf(khi);
                s = fmaf(klo * vreg[2 * q],     clo, s);
                s = fmaf(khi * vreg[2 * q + 1], chi, s);
            }
            #pragma unroll
            for (int m = 32; m; m >>= 1) s += __shfl_xor(s, m, 64);
            if (lane == 0) wsum += s * ulds[w * 8 + rr];
        }
        if (lane == 0) wlds[w] = wsum;
    }
    __syncthreads();
    if (t == 0) {
        float s = 0.f;
        #pragma unroll
        for (int g = 0; g < 8; g++) s += wlds[g];
        partials[idx] = s;
    }
}

// ---------------- final reduce ----------------
__global__ __launch_bounds__(256) void loss_final(
    const float* __restrict__ partials, float* __restrict__ out)
{
    int t = threadIdx.x;
    float s = partials[t];
    #pragma unroll
    for (int m = 32; m; m >>= 1) s += __shfl_xor(s, m, 64);
    __shared__ float wp[4];
    if ((t & 63) == 0) wp[t >> 6] = s;
    __syncthreads();
    if (t == 0) out[0] = (wp[0] + wp[1] + wp[2] + wp[3]) * (1.0f / 16.0f);
}

extern "C" void kernel_launch(void* const* d_in, const int* in_sizes, int n_in,
                              void* d_out, int out_size, void* d_ws, size_t ws_size,
                              hipStream_t stream) {
    const float* student = (const float*)d_in[0];
    const float* teacher = (const float*)d_in[1];
    float* out = (float*)d_out;
    char* ws = (char*)d_ws;

    unsigned short* Tn   = (unsigned short*)(ws);                     // 64 MB
    unsigned short* Sn   = (unsigned short*)(ws + 67108864);          // 64 MB
    unsigned short* Kmat = (unsigned short*)(ws + 134217728);         // 32 MB
    float*        tbuf     = (float*)(ws + 167772160);                // 256 KB
    unsigned int* flags    = (unsigned int*)(ws + 167772160 + 262144);// 4 KB
    float*        partials = (float*)(ws + 167772160 + 266240);       // 1 KB

    hipLaunchKernelGGL(init_state, dim3(64), dim3(256), 0, stream, tbuf, flags);
    hipLaunchKernelGGL(normalize_kernel, dim3(32768), dim3(256), 0, stream,
                       student, teacher, Sn, Tn);
    hipLaunchKernelGGL(gemm_cost_kernel, dim3(1024), dim3(256), 0, stream, Tn, Sn, Kmat);
    hipLaunchKernelGGL(sinkhorn_persistent, dim3(256), dim3(512), 0, stream,
                       Kmat, tbuf, flags, partials);
    hipLaunchKernelGGL(loss_final, dim3(1), dim3(256), 0, stream, partials, out);
}